// Round 8
// baseline (304.029 us; speedup 1.0000x reference)
//
#include <hip/hip_runtime.h>
#include <hip/hip_bf16.h>
#include <stdint.h>

typedef __bf16 bf16x4 __attribute__((ext_vector_type(4)));
typedef __bf16 bf16x8 __attribute__((ext_vector_type(8)));
typedef float  f32x4  __attribute__((ext_vector_type(4)));

#define LOG2E 1.44269504088896f

__device__ __forceinline__ bf16x8 cat8(bf16x4 a, bf16x4 b) {
    bf16x8 r;
    for (int i = 0; i < 4; ++i) { r[i] = a[i]; r[i + 4] = b[i]; }
    return r;
}

__device__ __forceinline__ void gl2lds16(const __bf16* g, __bf16* l) {
    __builtin_amdgcn_global_load_lds(
        (const __attribute__((address_space(1))) void*)g,
        (__attribute__((address_space(3))) void*)l, 16, 0, 0);
}

// ---------------- elementwise fp32 -> bf16 (grid exactly covers n, n % 2048 == 0) -------------
__global__ __launch_bounds__(256) void cvt_f32_bf16(const float* __restrict__ in,
                                                    __bf16* __restrict__ out) {
    size_t i = ((size_t)blockIdx.x * 256 + threadIdx.x) * 8;
    float4 a = ((const float4*)(in + i))[0];
    float4 b = ((const float4*)(in + i))[1];
    bf16x8 v;
    v[0] = (__bf16)a.x; v[1] = (__bf16)a.y; v[2] = (__bf16)a.z; v[3] = (__bf16)a.w;
    v[4] = (__bf16)b.x; v[5] = (__bf16)b.y; v[6] = (__bf16)b.z; v[7] = (__bf16)b.w;
    *(bf16x8*)(out + i) = v;
}

// ---------------- all-bf16 GEMM, m97 structure, 128x128 tile ---------------------------------
template<typename TC>
__global__ __launch_bounds__(256) void gemm_bt_bf16(
    const __bf16* __restrict__ A, const __bf16* __restrict__ B,
    const float* __restrict__ bias, TC* __restrict__ C,
    int M, int N, int K, int lda, int ldb, int ldc)
{
    __shared__ __bf16 As[128][32];
    __shared__ __bf16 Bs[128][32];
    const int tid = threadIdx.x;
    const int wave = tid >> 6, lane = tid & 63;
    const int lr = lane & 15, lq = lane >> 4;
    const int m0 = blockIdx.y * 128, n0 = blockIdx.x * 128;
    const int wm = (wave >> 1) * 64, wn = (wave & 1) * 64;

    f32x4 acc[4][4] = {};

    const int sr = lane >> 2;
    const int sc = (lane & 3) * 8;
    const __bf16* ag[2]; const __bf16* bg[2];
    __bf16* alds[2]; __bf16* blds[2];
    for (int t = 0; t < 2; ++t) {
        int chunk = wave * 2 + t;
        ag[t] = A + (size_t)(m0 + chunk * 16 + sr) * lda + sc;
        bg[t] = B + (size_t)(n0 + chunk * 16 + sr) * ldb + sc;
        alds[t] = &As[0][0] + chunk * 512;
        blds[t] = &Bs[0][0] + chunk * 512;
    }

    for (int k0 = 0; k0 < K; k0 += 32) {
        __syncthreads();
        gl2lds16(ag[0] + k0, alds[0]);
        gl2lds16(ag[1] + k0, alds[1]);
        gl2lds16(bg[0] + k0, blds[0]);
        gl2lds16(bg[1] + k0, blds[1]);
        __syncthreads();
        bf16x8 af[4], bf[4];
        for (int i = 0; i < 4; ++i) af[i] = *(const bf16x8*)&As[wm + i * 16 + lr][lq * 8];
        for (int j = 0; j < 4; ++j) bf[j] = *(const bf16x8*)&Bs[wn + j * 16 + lr][lq * 8];
        for (int i = 0; i < 4; ++i)
            for (int j = 0; j < 4; ++j)
                acc[i][j] = __builtin_amdgcn_mfma_f32_16x16x32_bf16(af[i], bf[j], acc[i][j], 0, 0, 0);
    }

    float bv[4] = {0.f, 0.f, 0.f, 0.f};
    if (bias)
        for (int j = 0; j < 4; ++j) bv[j] = bias[n0 + wn + j * 16 + lr];
    for (int i = 0; i < 4; ++i) {
        int row = m0 + wm + i * 16 + lq * 4;
        for (int j = 0; j < 4; ++j) {
            int col = n0 + wn + j * 16 + lr;
            for (int r = 0; r < 4; ++r) {
                float v = acc[i][j][r] + bv[j];
                C[(size_t)(row + r) * ldc + col] = (TC)v;
            }
        }
    }
}

// ---------------- all-bf16 GEMM, 128x64 tile (for small-N gemm2: 2x the blocks) ---------------
__global__ __launch_bounds__(256) void gemm_bt_bf16_n64(
    const __bf16* __restrict__ A, const __bf16* __restrict__ B,
    const float* __restrict__ bias, float* __restrict__ C,
    int M, int N, int K, int lda, int ldb, int ldc)
{
    __shared__ __bf16 As[128][32];
    __shared__ __bf16 Bs[64][32];
    const int tid = threadIdx.x;
    const int wave = tid >> 6, lane = tid & 63;
    const int lr = lane & 15, lq = lane >> 4;
    const int m0 = blockIdx.y * 128, n0 = blockIdx.x * 64;
    const int wm = wave * 32;   // each wave: 32(M) x 64(N)

    f32x4 acc[2][4] = {};

    const int sr = lane >> 2;
    const int sc = (lane & 3) * 8;
    const __bf16* gsrc[3]; __bf16* ldst[3];
    for (int t = 0; t < 3; ++t) {
        int c = wave * 3 + t;   // chunks 0..7 = A (128 rows), 8..11 = B (64 rows)
        if (c < 8) {
            gsrc[t] = A + (size_t)(m0 + c * 16 + sr) * lda + sc;
            ldst[t] = &As[0][0] + c * 512;
        } else {
            gsrc[t] = B + (size_t)(n0 + (c - 8) * 16 + sr) * ldb + sc;
            ldst[t] = &Bs[0][0] + (c - 8) * 512;
        }
    }

    for (int k0 = 0; k0 < K; k0 += 32) {
        __syncthreads();
        gl2lds16(gsrc[0] + k0, ldst[0]);
        gl2lds16(gsrc[1] + k0, ldst[1]);
        gl2lds16(gsrc[2] + k0, ldst[2]);
        __syncthreads();
        bf16x8 af[2], bf[4];
        for (int i = 0; i < 2; ++i) af[i] = *(const bf16x8*)&As[wm + i * 16 + lr][lq * 8];
        for (int j = 0; j < 4; ++j) bf[j] = *(const bf16x8*)&Bs[j * 16 + lr][lq * 8];
        for (int i = 0; i < 2; ++i)
            for (int j = 0; j < 4; ++j)
                acc[i][j] = __builtin_amdgcn_mfma_f32_16x16x32_bf16(af[i], bf[j], acc[i][j], 0, 0, 0);
    }

    float bv[4];
    for (int j = 0; j < 4; ++j) bv[j] = bias ? bias[n0 + j * 16 + lr] : 0.f;
    for (int i = 0; i < 2; ++i) {
        int row = m0 + wm + i * 16 + lq * 4;
        for (int j = 0; j < 4; ++j) {
            int col = n0 + j * 16 + lr;
            for (int r = 0; r < 4; ++r)
                C[(size_t)(row + r) * ldc + col] = acc[i][j][r] + bv[j];
        }
    }
}

// ---------------- fallback GEMM: fp32 ingest, stage16 cvt ------------------------------------
__device__ __forceinline__ void stage16(const float* __restrict__ g, __bf16* l) {
    float4 a = ((const float4*)g)[0];
    float4 b = ((const float4*)g)[1];
    float4 c = ((const float4*)g)[2];
    float4 d = ((const float4*)g)[3];
    bf16x8 lo, hi;
    lo[0] = (__bf16)a.x; lo[1] = (__bf16)a.y; lo[2] = (__bf16)a.z; lo[3] = (__bf16)a.w;
    lo[4] = (__bf16)b.x; lo[5] = (__bf16)b.y; lo[6] = (__bf16)b.z; lo[7] = (__bf16)b.w;
    hi[0] = (__bf16)c.x; hi[1] = (__bf16)c.y; hi[2] = (__bf16)c.z; hi[3] = (__bf16)c.w;
    hi[4] = (__bf16)d.x; hi[5] = (__bf16)d.y; hi[6] = (__bf16)d.z; hi[7] = (__bf16)d.w;
    ((bf16x8*)l)[0] = lo;
    ((bf16x8*)l)[1] = hi;
}
__device__ __forceinline__ void stage16(const __bf16* __restrict__ g, __bf16* l) {
    ((bf16x8*)l)[0] = ((const bf16x8*)g)[0];
    ((bf16x8*)l)[1] = ((const bf16x8*)g)[1];
}

template<typename TA, typename TB, typename TC>
__global__ __launch_bounds__(256) void gemm_bt(
    const TA* __restrict__ A, const TB* __restrict__ B,
    const float* __restrict__ bias, TC* __restrict__ C,
    int M, int N, int K, int lda, int ldb, int ldc)
{
    __shared__ __bf16 As[128][40];
    __shared__ __bf16 Bs[128][40];
    const int tid = threadIdx.x;
    const int wave = tid >> 6, lane = tid & 63;
    const int lr = lane & 15, lq = lane >> 4;
    const int m0 = blockIdx.y * 128, n0 = blockIdx.x * 128;
    const int wm = (wave >> 1) * 64, wn = (wave & 1) * 64;
    const int srow = tid >> 1, scol = (tid & 1) * 16;

    f32x4 acc[4][4] = {};
    const TA* agp = A + (size_t)(m0 + srow) * lda + scol;
    const TB* bgp = B + (size_t)(n0 + srow) * ldb + scol;

    for (int k0 = 0; k0 < K; k0 += 32) {
        __syncthreads();
        stage16(agp + k0, &As[srow][scol]);
        stage16(bgp + k0, &Bs[srow][scol]);
        __syncthreads();
        bf16x8 af[4], bf[4];
        for (int i = 0; i < 4; ++i) af[i] = *(const bf16x8*)&As[wm + i * 16 + lr][lq * 8];
        for (int j = 0; j < 4; ++j) bf[j] = *(const bf16x8*)&Bs[wn + j * 16 + lr][lq * 8];
        for (int i = 0; i < 4; ++i)
            for (int j = 0; j < 4; ++j)
                acc[i][j] = __builtin_amdgcn_mfma_f32_16x16x32_bf16(af[i], bf[j], acc[i][j], 0, 0, 0);
    }

    float bv[4] = {0.f, 0.f, 0.f, 0.f};
    if (bias)
        for (int j = 0; j < 4; ++j) bv[j] = bias[n0 + wn + j * 16 + lr];
    for (int i = 0; i < 4; ++i) {
        int row = m0 + wm + i * 16 + lq * 4;
        for (int j = 0; j < 4; ++j) {
            int col = n0 + wn + j * 16 + lr;
            for (int r = 0; r < 4; ++r) {
                float v = acc[i][j][r] + bv[j];
                C[(size_t)(row + r) * ldc + col] = (TC)v;
            }
        }
    }
}

// ---------------- flash attention v3: double-buffered LDS, ONE barrier/iter ------------------
// Transposed-S (Q as B-operand), fixed-shift softmax, raw v_exp_f32, Vt stored in pseudo-k
// packed column order so the PV A-fragment is a single b128 read (and transpose writes hit
// 2-way banks only). Single barrier covers RAW (new buf) + WAR (buf about to be overwritten).
__global__ __launch_bounds__(256) void attn_kernel(__bf16* __restrict__ qkv)
{
    __shared__ __bf16 Ks[2][64][72];   // [buf][j][d], padded
    __shared__ __bf16 Vt[2][64][72];   // [buf][d][j' packed], padded (cols 0..63 used)

    const int tid = threadIdx.x;
    const int wave = tid >> 6, lane = tid & 63;
    const int lr = lane & 15, lq = lane >> 4;

    const int bid = blockIdx.x;
    const int xcd = bid & 7, slot = bid >> 3;
    const int bh = xcd * 8 + (slot >> 4);
    const int qt = slot & 15;
    const int b = bh >> 4, h = bh & 15;
    const int rowbase = b * 2048;
    const int q0 = qt * 128;
    const float c1 = 0.125f * LOG2E;
    const float SHIFT = 8.0f;

    // Q fragments (B-operand layout: n=lr -> Q row, k=lq*8 -> d chunk)
    bf16x8 qf[2][2];
    for (int mt = 0; mt < 2; ++mt)
        for (int ks = 0; ks < 2; ++ks)
            qf[mt][ks] = *(const bf16x8*)(qkv +
                (size_t)(rowbase + q0 + wave * 32 + mt * 16 + lr) * 3072 + h * 64 + ks * 32 + lq * 8);

    float l_lane[2] = {0.f, 0.f};
    f32x4 o_acc[2][4] = {};            // [mt][dt], O^T C-layout: col=lr=i, row=(lq,reg)=d

    const int kr = tid >> 2, kc = (tid & 3) * 16;   // K staging: 32B of one row
    const int g0 = tid & 15;
    const int vj0 = g0 * 4, vd0 = (tid >> 4) * 4;   // V: 4x4 register transpose
    // packed column for j-group g0: pi*32 + (g&3)*8 + bit2(g)*4
    const int vcol = ((g0 >> 3) * 32) + ((g0 & 3) * 8) + (((g0 >> 2) & 1) * 4);
    const __bf16* kbase = qkv + (size_t)(rowbase + kr) * 3072 + 1024 + h * 64 + kc;
    const __bf16* vbase = qkv + (size_t)(rowbase + vj0) * 3072 + 2048 + h * 64 + vd0;

    // tile 0 -> regs -> buf 0
    bf16x8 ka = ((const bf16x8*)kbase)[0];
    bf16x8 kb = ((const bf16x8*)kbase)[1];
    uint2 t0 = *(const uint2*)(vbase);
    uint2 t1 = *(const uint2*)(vbase + 3072);
    uint2 t2 = *(const uint2*)(vbase + 6144);
    uint2 t3 = *(const uint2*)(vbase + 9216);
    {
        *(bf16x8*)&Ks[0][kr][kc] = ka;
        *(bf16x8*)(&Ks[0][kr][kc] + 8) = kb;
        uint2 c0 = { (t0.x & 0xffffu) | (t1.x << 16), (t2.x & 0xffffu) | (t3.x << 16) };
        uint2 d1 = { (t0.x >> 16) | (t1.x & 0xffff0000u), (t2.x >> 16) | (t3.x & 0xffff0000u) };
        uint2 c2 = { (t0.y & 0xffffu) | (t1.y << 16), (t2.y & 0xffffu) | (t3.y << 16) };
        uint2 d3 = { (t0.y >> 16) | (t1.y & 0xffff0000u), (t2.y >> 16) | (t3.y & 0xffff0000u) };
        *(uint2*)&Vt[0][vd0 + 0][vcol] = c0;
        *(uint2*)&Vt[0][vd0 + 1][vcol] = d1;
        *(uint2*)&Vt[0][vd0 + 2][vcol] = c2;
        *(uint2*)&Vt[0][vd0 + 3][vcol] = d3;
    }

    for (int it = 0; it < 32; ++it) {
        const int cur = it & 1;
        __syncthreads();   // RAW: buf cur visible; WAR: everyone done reading buf cur^1

        if (it + 1 < 32) {   // issue next tile's global loads; land during compute
            const __bf16* kg = kbase + (size_t)(it + 1) * 64 * 3072;
            ka = ((const bf16x8*)kg)[0];
            kb = ((const bf16x8*)kg)[1];
            const __bf16* vg = vbase + (size_t)(it + 1) * 64 * 3072;
            t0 = *(const uint2*)(vg);
            t1 = *(const uint2*)(vg + 3072);
            t2 = *(const uint2*)(vg + 6144);
            t3 = *(const uint2*)(vg + 9216);
        }

        // --- S^T[j][i] = sum_d K[j][d] Q[i][d];  j=ntj*16+lq*4+reg, i=mt*16+lr ---
        f32x4 s[2][4] = {};
        for (int ks = 0; ks < 2; ++ks) {
            bf16x8 kf[4];
            for (int ntj = 0; ntj < 4; ++ntj)
                kf[ntj] = *(const bf16x8*)&Ks[cur][ntj * 16 + lr][ks * 32 + lq * 8];
            for (int mt = 0; mt < 2; ++mt)
                for (int ntj = 0; ntj < 4; ++ntj)
                    s[mt][ntj] = __builtin_amdgcn_mfma_f32_16x16x32_bf16(kf[ntj], qf[mt][ks], s[mt][ntj], 0, 0, 0);
        }

        // --- softmax numerator: fma + raw v_exp_f32 + cvt + add per element ---
        bf16x4 pf[2][4];
        for (int mt = 0; mt < 2; ++mt) {
            for (int ntj = 0; ntj < 4; ++ntj) {
                bf16x4 pk;
                for (int r = 0; r < 4; ++r) {
                    float p = __builtin_amdgcn_exp2f(s[mt][ntj][r] * c1 - SHIFT);
                    l_lane[mt] += p;
                    pk[r] = (__bf16)p;
                }
                pf[mt][ntj] = pk;
            }
        }

        // --- O^T += V^T P: V-fragment is one b128 read (packed layout) ---
        for (int pi = 0; pi < 2; ++pi) {
            bf16x8 pfrag[2];
            for (int mt = 0; mt < 2; ++mt)
                pfrag[mt] = cat8(pf[mt][2 * pi], pf[mt][2 * pi + 1]);
            for (int dt = 0; dt < 4; ++dt) {
                bf16x8 vf = *(const bf16x8*)&Vt[cur][dt * 16 + lr][pi * 32 + lq * 8];
                for (int mt = 0; mt < 2; ++mt)
                    o_acc[mt][dt] = __builtin_amdgcn_mfma_f32_16x16x32_bf16(vf, pfrag[mt], o_acc[mt][dt], 0, 0, 0);
            }
        }

        // --- stage next tile into the other buffer (no barrier needed here) ---
        if (it + 1 < 32) {
            const int nb = cur ^ 1;
            *(bf16x8*)&Ks[nb][kr][kc] = ka;
            *(bf16x8*)(&Ks[nb][kr][kc] + 8) = kb;
            uint2 c0 = { (t0.x & 0xffffu) | (t1.x << 16), (t2.x & 0xffffu) | (t3.x << 16) };
            uint2 d1 = { (t0.x >> 16) | (t1.x & 0xffff0000u), (t2.x >> 16) | (t3.x & 0xffff0000u) };
            uint2 c2 = { (t0.y & 0xffffu) | (t1.y << 16), (t2.y & 0xffffu) | (t3.y << 16) };
            uint2 d3 = { (t0.y >> 16) | (t1.y & 0xffff0000u), (t2.y >> 16) | (t3.y & 0xffff0000u) };
            *(uint2*)&Vt[nb][vd0 + 0][vcol] = c0;
            *(uint2*)&Vt[nb][vd0 + 1][vcol] = d1;
            *(uint2*)&Vt[nb][vd0 + 2][vcol] = c2;
            *(uint2*)&Vt[nb][vd0 + 3][vcol] = d3;
        }
    }

    // --- epilogue: reduce l across lq lanes, O^T/l -> Q region, b64 stores ---
    for (int mt = 0; mt < 2; ++mt) {
        float l = l_lane[mt];
        l += __shfl_xor(l, 16);
        l += __shfl_xor(l, 32);
        float inv = 1.f / l;
        for (int dt = 0; dt < 4; ++dt) {
            bf16x4 ob;
            for (int r = 0; r < 4; ++r) ob[r] = (__bf16)(o_acc[mt][dt][r] * inv);
            *(bf16x4*)(qkv + (size_t)(rowbase + q0 + wave * 32 + mt * 16 + lr) * 3072 +
                       h * 64 + dt * 16 + lq * 4) = ob;
        }
    }
}

extern "C" void kernel_launch(void* const* d_in, const int* in_sizes, int n_in,
                              void* d_out, int out_size, void* d_ws, size_t ws_size,
                              hipStream_t stream) {
    const float* x     = (const float*)d_in[0];   // [8192, 1024] fp32
    const float* Wqkv  = (const float*)d_in[1];   // [3072, 1024] fp32
    const float* Wproj = (const float*)d_in[2];   // [1024, 1024] fp32
    const float* bproj = (const float*)d_in[3];   // [1024] fp32
    float* out   = (float*)d_out;                 // [8192, 1024] fp32
    __bf16* qkvb = (__bf16*)d_ws;                 // [8192, 3072] bf16

    const size_t QKV_E = (size_t)8192 * 3072;
    const size_t X_E   = (size_t)8192 * 1024;
    const size_t WQ_E  = (size_t)3072 * 1024;
    const size_t WP_E  = (size_t)1024 * 1024;
    const bool fast = ws_size >= (QKV_E + X_E + WQ_E + WP_E) * sizeof(__bf16);

    if (fast) {
        __bf16* xb  = qkvb + QKV_E;
        __bf16* wqb = xb + X_E;
        __bf16* wpb = wqb + WQ_E;
        cvt_f32_bf16<<<dim3((unsigned)(X_E / 2048)),  256, 0, stream>>>(x, xb);
        cvt_f32_bf16<<<dim3((unsigned)(WQ_E / 2048)), 256, 0, stream>>>(Wqkv, wqb);
        cvt_f32_bf16<<<dim3((unsigned)(WP_E / 2048)), 256, 0, stream>>>(Wproj, wpb);
        gemm_bt_bf16<__bf16><<<dim3(24, 64), 256, 0, stream>>>(
            xb, wqb, nullptr, qkvb, 8192, 3072, 1024, 1024, 1024, 3072);
        attn_kernel<<<dim3(1024), 256, 0, stream>>>(qkvb);
        gemm_bt_bf16_n64<<<dim3(16, 64), 256, 0, stream>>>(
            qkvb, wpb, bproj, out, 8192, 1024, 1024, 3072, 1024, 1024);
    } else {
        gemm_bt<float, float, __bf16><<<dim3(24, 64), 256, 0, stream>>>(
            x, Wqkv, nullptr, qkvb, 8192, 3072, 1024, 1024, 1024, 3072);
        attn_kernel<<<dim3(1024), 256, 0, stream>>>(qkvb);
        gemm_bt<__bf16, float, float><<<dim3(8, 64), 256, 0, stream>>>(
            qkvb, Wproj, bproj, out, 8192, 1024, 1024, 3072, 1024, 1024);
    }
}

// Round 9
// 281.592 us; speedup vs baseline: 1.0797x; 1.0797x over previous
//
#include <hip/hip_runtime.h>
#include <hip/hip_bf16.h>
#include <stdint.h>

typedef __bf16 bf16x4 __attribute__((ext_vector_type(4)));
typedef __bf16 bf16x8 __attribute__((ext_vector_type(8)));
typedef float  f32x4  __attribute__((ext_vector_type(4)));

#define LOG2E 1.44269504088896f

__device__ __forceinline__ void gl2lds16(const __bf16* g, __bf16* l) {
    __builtin_amdgcn_global_load_lds(
        (const __attribute__((address_space(1))) void*)g,
        (__attribute__((address_space(3))) void*)l, 16, 0, 0);
}

// ---------------- elementwise fp32 -> bf16 (grid exactly covers n, n % 2048 == 0) -------------
__global__ __launch_bounds__(256) void cvt_f32_bf16(const float* __restrict__ in,
                                                    __bf16* __restrict__ out) {
    size_t i = ((size_t)blockIdx.x * 256 + threadIdx.x) * 8;
    float4 a = ((const float4*)(in + i))[0];
    float4 b = ((const float4*)(in + i))[1];
    bf16x8 v;
    v[0] = (__bf16)a.x; v[1] = (__bf16)a.y; v[2] = (__bf16)a.z; v[3] = (__bf16)a.w;
    v[4] = (__bf16)b.x; v[5] = (__bf16)b.y; v[6] = (__bf16)b.z; v[7] = (__bf16)b.w;
    *(bf16x8*)(out + i) = v;
}

// ---------------- all-bf16 GEMM, m97 structure, 128x128 tile ---------------------------------
template<typename TC>
__global__ __launch_bounds__(256) void gemm_bt_bf16(
    const __bf16* __restrict__ A, const __bf16* __restrict__ B,
    const float* __restrict__ bias, TC* __restrict__ C,
    int M, int N, int K, int lda, int ldb, int ldc)
{
    __shared__ __bf16 As[128][32];
    __shared__ __bf16 Bs[128][32];
    const int tid = threadIdx.x;
    const int wave = tid >> 6, lane = tid & 63;
    const int lr = lane & 15, lq = lane >> 4;
    const int m0 = blockIdx.y * 128, n0 = blockIdx.x * 128;
    const int wm = (wave >> 1) * 64, wn = (wave & 1) * 64;

    f32x4 acc[4][4] = {};

    const int sr = lane >> 2;
    const int sc = (lane & 3) * 8;
    const __bf16* ag[2]; const __bf16* bg[2];
    __bf16* alds[2]; __bf16* blds[2];
    for (int t = 0; t < 2; ++t) {
        int chunk = wave * 2 + t;
        ag[t] = A + (size_t)(m0 + chunk * 16 + sr) * lda + sc;
        bg[t] = B + (size_t)(n0 + chunk * 16 + sr) * ldb + sc;
        alds[t] = &As[0][0] + chunk * 512;
        blds[t] = &Bs[0][0] + chunk * 512;
    }

    for (int k0 = 0; k0 < K; k0 += 32) {
        __syncthreads();
        gl2lds16(ag[0] + k0, alds[0]);
        gl2lds16(ag[1] + k0, alds[1]);
        gl2lds16(bg[0] + k0, blds[0]);
        gl2lds16(bg[1] + k0, blds[1]);
        __syncthreads();
        bf16x8 af[4], bf[4];
        for (int i = 0; i < 4; ++i) af[i] = *(const bf16x8*)&As[wm + i * 16 + lr][lq * 8];
        for (int j = 0; j < 4; ++j) bf[j] = *(const bf16x8*)&Bs[wn + j * 16 + lr][lq * 8];
        for (int i = 0; i < 4; ++i)
            for (int j = 0; j < 4; ++j)
                acc[i][j] = __builtin_amdgcn_mfma_f32_16x16x32_bf16(af[i], bf[j], acc[i][j], 0, 0, 0);
    }

    float bv[4] = {0.f, 0.f, 0.f, 0.f};
    if (bias)
        for (int j = 0; j < 4; ++j) bv[j] = bias[n0 + wn + j * 16 + lr];
    for (int i = 0; i < 4; ++i) {
        int row = m0 + wm + i * 16 + lq * 4;
        for (int j = 0; j < 4; ++j) {
            int col = n0 + wn + j * 16 + lr;
            for (int r = 0; r < 4; ++r) {
                float v = acc[i][j][r] + bv[j];
                C[(size_t)(row + r) * ldc + col] = (TC)v;
            }
        }
    }
}

// ---------------- fallback GEMM: fp32 ingest, stage16 cvt ------------------------------------
__device__ __forceinline__ void stage16(const float* __restrict__ g, __bf16* l) {
    float4 a = ((const float4*)g)[0];
    float4 b = ((const float4*)g)[1];
    float4 c = ((const float4*)g)[2];
    float4 d = ((const float4*)g)[3];
    bf16x8 lo, hi;
    lo[0] = (__bf16)a.x; lo[1] = (__bf16)a.y; lo[2] = (__bf16)a.z; lo[3] = (__bf16)a.w;
    lo[4] = (__bf16)b.x; lo[5] = (__bf16)b.y; lo[6] = (__bf16)b.z; lo[7] = (__bf16)b.w;
    hi[0] = (__bf16)c.x; hi[1] = (__bf16)c.y; hi[2] = (__bf16)c.z; hi[3] = (__bf16)c.w;
    hi[4] = (__bf16)d.x; hi[5] = (__bf16)d.y; hi[6] = (__bf16)d.z; hi[7] = (__bf16)d.w;
    ((bf16x8*)l)[0] = lo;
    ((bf16x8*)l)[1] = hi;
}
__device__ __forceinline__ void stage16(const __bf16* __restrict__ g, __bf16* l) {
    ((bf16x8*)l)[0] = ((const bf16x8*)g)[0];
    ((bf16x8*)l)[1] = ((const bf16x8*)g)[1];
}

template<typename TA, typename TB, typename TC>
__global__ __launch_bounds__(256) void gemm_bt(
    const TA* __restrict__ A, const TB* __restrict__ B,
    const float* __restrict__ bias, TC* __restrict__ C,
    int M, int N, int K, int lda, int ldb, int ldc)
{
    __shared__ __bf16 As[128][40];
    __shared__ __bf16 Bs[128][40];
    const int tid = threadIdx.x;
    const int wave = tid >> 6, lane = tid & 63;
    const int lr = lane & 15, lq = lane >> 4;
    const int m0 = blockIdx.y * 128, n0 = blockIdx.x * 128;
    const int wm = (wave >> 1) * 64, wn = (wave & 1) * 64;
    const int srow = tid >> 1, scol = (tid & 1) * 16;

    f32x4 acc[4][4] = {};
    const TA* agp = A + (size_t)(m0 + srow) * lda + scol;
    const TB* bgp = B + (size_t)(n0 + srow) * ldb + scol;

    for (int k0 = 0; k0 < K; k0 += 32) {
        __syncthreads();
        stage16(agp + k0, &As[srow][scol]);
        stage16(bgp + k0, &Bs[srow][scol]);
        __syncthreads();
        bf16x8 af[4], bf[4];
        for (int i = 0; i < 4; ++i) af[i] = *(const bf16x8*)&As[wm + i * 16 + lr][lq * 8];
        for (int j = 0; j < 4; ++j) bf[j] = *(const bf16x8*)&Bs[wn + j * 16 + lr][lq * 8];
        for (int i = 0; i < 4; ++i)
            for (int j = 0; j < 4; ++j)
                acc[i][j] = __builtin_amdgcn_mfma_f32_16x16x32_bf16(af[i], bf[j], acc[i][j], 0, 0, 0);
    }

    float bv[4] = {0.f, 0.f, 0.f, 0.f};
    if (bias)
        for (int j = 0; j < 4; ++j) bv[j] = bias[n0 + wn + j * 16 + lr];
    for (int i = 0; i < 4; ++i) {
        int row = m0 + wm + i * 16 + lq * 4;
        for (int j = 0; j < 4; ++j) {
            int col = n0 + wn + j * 16 + lr;
            for (int r = 0; r < 4; ++r) {
                float v = acc[i][j][r] + bv[j];
                C[(size_t)(row + r) * ldc + col] = (TC)v;
            }
        }
    }
}

// ---------------- flash attention v4: BM=256 (wave=64 Q rows), 4 MFMA per LDS read -----------
// Transposed-S (Q as B-operand), fixed-shift softmax (raw v_exp_f32), double-buffered LDS,
// one barrier/iter, packed-Vt so PV A-fragment is one b128 read, pi-split softmax/PV to cap
// register live range, exp results written directly into the packed B-fragment (no cat8 movs).
__global__ __launch_bounds__(256, 2) void attn_kernel(__bf16* __restrict__ qkv)
{
    __shared__ __bf16 Ks[2][64][72];   // [buf][j][d], padded
    __shared__ __bf16 Vt[2][64][72];   // [buf][d][j' packed], padded

    const int tid = threadIdx.x;
    const int wave = tid >> 6, lane = tid & 63;
    const int lr = lane & 15, lq = lane >> 4;

    const int bid = blockIdx.x;          // 512 blocks: 64 bh x 8 qt
    const int xcd = bid & 7, slot = bid >> 3;
    const int bh = xcd * 8 + (slot >> 3);
    const int qt = slot & 7;
    const int b = bh >> 4, h = bh & 15;
    const int rowbase = b * 2048;
    const int q0 = qt * 256;
    const float c1 = 0.125f * LOG2E;
    const float SHIFT = 8.0f;

    // Q fragments (B-operand layout: n=lr -> Q row, k=lq*8 -> d chunk); wave owns 64 rows
    bf16x8 qf[4][2];
    for (int mt = 0; mt < 4; ++mt)
        for (int ks = 0; ks < 2; ++ks)
            qf[mt][ks] = *(const bf16x8*)(qkv +
                (size_t)(rowbase + q0 + wave * 64 + mt * 16 + lr) * 3072 + h * 64 + ks * 32 + lq * 8);

    float l_lane[4] = {0.f, 0.f, 0.f, 0.f};
    f32x4 o_acc[4][4] = {};            // [mt][dt], O^T C-layout: col=lr=i, row=(lq,reg)=d

    const int kr = tid >> 2, kc = (tid & 3) * 16;   // K staging: 32B of one row
    const int g0 = tid & 15;
    const int vj0 = g0 * 4, vd0 = (tid >> 4) * 4;   // V: 4x4 register transpose
    const int vcol = ((g0 >> 3) * 32) + ((g0 & 3) * 8) + (((g0 >> 2) & 1) * 4);
    const __bf16* kbase = qkv + (size_t)(rowbase + kr) * 3072 + 1024 + h * 64 + kc;
    const __bf16* vbase = qkv + (size_t)(rowbase + vj0) * 3072 + 2048 + h * 64 + vd0;

    // tile 0 -> regs -> buf 0
    bf16x8 ka = ((const bf16x8*)kbase)[0];
    bf16x8 kb = ((const bf16x8*)kbase)[1];
    uint2 t0 = *(const uint2*)(vbase);
    uint2 t1 = *(const uint2*)(vbase + 3072);
    uint2 t2 = *(const uint2*)(vbase + 6144);
    uint2 t3 = *(const uint2*)(vbase + 9216);
    {
        *(bf16x8*)&Ks[0][kr][kc] = ka;
        *(bf16x8*)(&Ks[0][kr][kc] + 8) = kb;
        uint2 c0 = { (t0.x & 0xffffu) | (t1.x << 16), (t2.x & 0xffffu) | (t3.x << 16) };
        uint2 d1 = { (t0.x >> 16) | (t1.x & 0xffff0000u), (t2.x >> 16) | (t3.x & 0xffff0000u) };
        uint2 c2 = { (t0.y & 0xffffu) | (t1.y << 16), (t2.y & 0xffffu) | (t3.y << 16) };
        uint2 d3 = { (t0.y >> 16) | (t1.y & 0xffff0000u), (t2.y >> 16) | (t3.y & 0xffff0000u) };
        *(uint2*)&Vt[0][vd0 + 0][vcol] = c0;
        *(uint2*)&Vt[0][vd0 + 1][vcol] = d1;
        *(uint2*)&Vt[0][vd0 + 2][vcol] = c2;
        *(uint2*)&Vt[0][vd0 + 3][vcol] = d3;
    }

    for (int it = 0; it < 32; ++it) {
        const int cur = it & 1;
        __syncthreads();   // RAW: buf cur visible; WAR: everyone done with buf cur^1

        if (it + 1 < 32) {   // issue next tile's global loads; land during compute
            const __bf16* kg = kbase + (size_t)(it + 1) * 64 * 3072;
            ka = ((const bf16x8*)kg)[0];
            kb = ((const bf16x8*)kg)[1];
            const __bf16* vg = vbase + (size_t)(it + 1) * 64 * 3072;
            t0 = *(const uint2*)(vg);
            t1 = *(const uint2*)(vg + 3072);
            t2 = *(const uint2*)(vg + 6144);
            t3 = *(const uint2*)(vg + 9216);
        }

        for (int pi = 0; pi < 2; ++pi) {
            // --- S^T: j in [pi*32, pi*32+32), all 64 Q rows of this wave ---
            f32x4 s[4][2] = {};
            for (int ks = 0; ks < 2; ++ks) {
                bf16x8 kf0 = *(const bf16x8*)&Ks[cur][(2 * pi + 0) * 16 + lr][ks * 32 + lq * 8];
                bf16x8 kf1 = *(const bf16x8*)&Ks[cur][(2 * pi + 1) * 16 + lr][ks * 32 + lq * 8];
                for (int mt = 0; mt < 4; ++mt) {
                    s[mt][0] = __builtin_amdgcn_mfma_f32_16x16x32_bf16(kf0, qf[mt][ks], s[mt][0], 0, 0, 0);
                    s[mt][1] = __builtin_amdgcn_mfma_f32_16x16x32_bf16(kf1, qf[mt][ks], s[mt][1], 0, 0, 0);
                }
            }
            // --- softmax numerator -> packed B-fragment directly ---
            bf16x8 pfrag[4];
            for (int mt = 0; mt < 4; ++mt) {
                for (int t = 0; t < 2; ++t)
                    for (int r = 0; r < 4; ++r) {
                        float p = __builtin_amdgcn_exp2f(s[mt][t][r] * c1 - SHIFT);
                        l_lane[mt] += p;
                        pfrag[mt][t * 4 + r] = (__bf16)p;
                    }
            }
            // --- O^T += V^T P (V-fragment = one b128 read, reused across 4 mt) ---
            for (int dt = 0; dt < 4; ++dt) {
                bf16x8 vf = *(const bf16x8*)&Vt[cur][dt * 16 + lr][pi * 32 + lq * 8];
                for (int mt = 0; mt < 4; ++mt)
                    o_acc[mt][dt] = __builtin_amdgcn_mfma_f32_16x16x32_bf16(vf, pfrag[mt], o_acc[mt][dt], 0, 0, 0);
            }
        }

        // --- stage next tile into the other buffer (no barrier needed here) ---
        if (it + 1 < 32) {
            const int nb = cur ^ 1;
            *(bf16x8*)&Ks[nb][kr][kc] = ka;
            *(bf16x8*)(&Ks[nb][kr][kc] + 8) = kb;
            uint2 c0 = { (t0.x & 0xffffu) | (t1.x << 16), (t2.x & 0xffffu) | (t3.x << 16) };
            uint2 d1 = { (t0.x >> 16) | (t1.x & 0xffff0000u), (t2.x >> 16) | (t3.x & 0xffff0000u) };
            uint2 c2 = { (t0.y & 0xffffu) | (t1.y << 16), (t2.y & 0xffffu) | (t3.y << 16) };
            uint2 d3 = { (t0.y >> 16) | (t1.y & 0xffff0000u), (t2.y >> 16) | (t3.y & 0xffff0000u) };
            *(uint2*)&Vt[nb][vd0 + 0][vcol] = c0;
            *(uint2*)&Vt[nb][vd0 + 1][vcol] = d1;
            *(uint2*)&Vt[nb][vd0 + 2][vcol] = c2;
            *(uint2*)&Vt[nb][vd0 + 3][vcol] = d3;
        }
    }

    // --- epilogue: reduce l across lq lanes, O^T/l -> Q region, b64 stores ---
    for (int mt = 0; mt < 4; ++mt) {
        float l = l_lane[mt];
        l += __shfl_xor(l, 16);
        l += __shfl_xor(l, 32);
        float inv = 1.f / l;
        for (int dt = 0; dt < 4; ++dt) {
            bf16x4 ob;
            for (int r = 0; r < 4; ++r) ob[r] = (__bf16)(o_acc[mt][dt][r] * inv);
            *(bf16x4*)(qkv + (size_t)(rowbase + q0 + wave * 64 + mt * 16 + lr) * 3072 +
                       h * 64 + dt * 16 + lq * 4) = ob;
        }
    }
}

extern "C" void kernel_launch(void* const* d_in, const int* in_sizes, int n_in,
                              void* d_out, int out_size, void* d_ws, size_t ws_size,
                              hipStream_t stream) {
    const float* x     = (const float*)d_in[0];   // [8192, 1024] fp32
    const float* Wqkv  = (const float*)d_in[1];   // [3072, 1024] fp32
    const float* Wproj = (const float*)d_in[2];   // [1024, 1024] fp32
    const float* bproj = (const float*)d_in[3];   // [1024] fp32
    float* out   = (float*)d_out;                 // [8192, 1024] fp32
    __bf16* qkvb = (__bf16*)d_ws;                 // [8192, 3072] bf16

    const size_t QKV_E = (size_t)8192 * 3072;
    const size_t X_E   = (size_t)8192 * 1024;
    const size_t WQ_E  = (size_t)3072 * 1024;
    const size_t WP_E  = (size_t)1024 * 1024;
    const bool fast = ws_size >= (QKV_E + X_E + WQ_E + WP_E) * sizeof(__bf16);

    if (fast) {
        __bf16* xb  = qkvb + QKV_E;
        __bf16* wqb = xb + X_E;
        __bf16* wpb = wqb + WQ_E;
        cvt_f32_bf16<<<dim3((unsigned)(X_E / 2048)),  256, 0, stream>>>(x, xb);
        cvt_f32_bf16<<<dim3((unsigned)(WQ_E / 2048)), 256, 0, stream>>>(Wqkv, wqb);
        cvt_f32_bf16<<<dim3((unsigned)(WP_E / 2048)), 256, 0, stream>>>(Wproj, wpb);
        gemm_bt_bf16<__bf16><<<dim3(24, 64), 256, 0, stream>>>(
            xb, wqb, nullptr, qkvb, 8192, 3072, 1024, 1024, 1024, 3072);
        attn_kernel<<<dim3(512), 256, 0, stream>>>(qkvb);
        gemm_bt_bf16<float><<<dim3(8, 64), 256, 0, stream>>>(
            qkvb, wpb, bproj, out, 8192, 1024, 1024, 3072, 1024, 1024);
    } else {
        gemm_bt<float, float, __bf16><<<dim3(24, 64), 256, 0, stream>>>(
            x, Wqkv, nullptr, qkvb, 8192, 3072, 1024, 1024, 1024, 3072);
        attn_kernel<<<dim3(512), 256, 0, stream>>>(qkvb);
        gemm_bt<__bf16, float, float><<<dim3(8, 64), 256, 0, stream>>>(
            qkvb, Wproj, bproj, out, 8192, 1024, 1024, 3072, 1024, 1024);
    }
}